// Round 6
// baseline (186.782 us; speedup 1.0000x reference)
//
#include <hip/hip_runtime.h>
#include <math.h>

// [B=2, 1, D=192, H=192, W=192] fp32
#define W 192
#define H 192
#define DEPTH 192
#define BATCH 2
#define TW 64          // tile width
#define TH 8           // tile height
#define DC 12          // output planes per block -> grid 72*16*2 = 2304 blocks
#define HW (H * W)
#define VOL ((size_t)DEPTH * HW)
#define LROW 72        // LDS row stride (floats), = aligned halo row [w0-4, w0+68)
#define LPLANE (LROW * 10)            // 720 floats per plane tile
#define NPAIR ((DC + 2) / 2)          // 7 pairs of planes: d0-1 .. d0+12
#define NITEM 720                     // float4 items per pair: 2 arrays * 2 planes * 10 rows * 18
#define NBUF 3                        // 3-deep LDS rotation (prefetch depth 2 pairs)
#define BUFFLOATS 3072                // 768 items * 4 floats (720 used + 48 pad for OOB lanes)

// Zero page for OOB DMA sources (explicitly zero-initialized).
__device__ __align__(16) float g_zero16[16] = {0.f};

// Round-4 proven compute geometry (wave-owns-row-pair, 0 bank conflicts).
// Round-5/6 change: staging via global_load_lds DMA into a 3-buffer rotation with
// counted s_waitcnt vmcnt(3) + raw s_barrier (one barrier per pair, never a full
// vmcnt(0) drain in the loop). LDS item layout is linear in item index j
// (byte = 16*j), exactly matching the DMA's wave-uniform-base + lane*16 contract:
//   4*j = (a*2+q)*LPLANE + r*LROW + 4*c  (verified identity with compute reads).
__global__ __launch_bounds__(256) void sobel_loss_part(
    const float* __restrict__ pred, const float* __restrict__ gt,
    const float* __restrict__ mask, float* __restrict__ partials)
{
    __shared__ __align__(16) float lds[NBUF * BUFFLOATS];
    __shared__ float red[4];

    const int tid = threadIdx.x;
    const int tx = blockIdx.x % 3;          // W tile (0..2)
    const int ty = blockIdx.x / 3;          // H tile (0..23)
    const int w0 = tx * TW, h0 = ty * TH;
    const int d0 = blockIdx.y * DC;
    const size_t base = (size_t)blockIdx.z * VOL;

    // compute-thread geometry: wave wv owns rows (2wv, 2wv+1); lane = column
    const int wv  = tid >> 6;               // wave 0..3 -> row pair
    const int col = tid & 63;               // column 0..63
    const size_t moff = base + (size_t)(h0 + 2 * wv) * W + (w0 + col);  // row A; row B = +W

    // ---- staging geometry (3 DMA items/thread, loop-invariant) ----
    // j = tid + 256k: a=j/360 (0=pred,1=gt), q=plane in pair, r=row 0..9, c=col4 0..17
    // LDS float offset within buffer = 4*j (linear); j>=720 lanes write zeros into pad.
    int it_ok[3], it_q[3];
    size_t it_goff[3];
    const float* it_src[3];
    #pragma unroll
    for (int k = 0; k < 3; ++k) {
        int j = tid + 256 * k;
        int jj = (j < NITEM) ? j : 0;
        int a = jj / 360; int pj = jj - a * 360;
        int q = pj / 180; int e = pj - q * 180;
        int r = e / 18;   int c = e - r * 18;
        int y  = h0 - 1 + r;
        int xf = w0 - 4 + 4 * c;            // 16B aligned; OOB float4s are fully OOB
        it_ok[k]  = (j < NITEM) && ((unsigned)y < (unsigned)H) && ((unsigned)xf < (unsigned)W);
        it_goff[k] = it_ok[k] ? ((size_t)y * W + xf) : 0;
        it_q[k]    = q;
        it_src[k]  = a ? gt : pred;
    }

    typedef const __attribute__((address_space(1))) void GV;
    typedef __attribute__((address_space(3))) void LV;

    auto dma_pair = [&](int s) {
        float* bufp = lds + (s % NBUF) * BUFFLOATS;
        const int p0 = d0 - 1 + 2 * s;
        #pragma unroll
        for (int k = 0; k < 3; ++k) {
            const int p = p0 + it_q[k];
            const bool v = it_ok[k] && (p >= 0) && (p < DEPTH);
            const float* ga = v ? (it_src[k] + base + (size_t)p * HW + it_goff[k])
                               : g_zero16;
            // LDS dest: wave-uniform base (16*(wv*64+256k) bytes) + lane*16 (HW-applied)
            __builtin_amdgcn_global_load_lds((GV*)ga,
                (LV*)(bufp + (((wv << 6) + (k << 8)) << 2)), 16, 0, 0);
        }
    };

    float2 Mn = make_float2(0.f, 0.f), Mn1 = make_float2(0.f, 0.f);
    float2 Mc, Mc1;
    auto load_mask = [&](int s) {   // masks for round s outputs: planes d0+2s-2, d0+2s-1
        const size_t p0 = moff + (size_t)(d0 + 2 * s - 2) * HW;
        Mn  = make_float2(mask[p0], mask[p0 + W]);            // .x = row A, .y = row B
        Mn1 = make_float2(mask[p0 + HW], mask[p0 + HW + W]);
    };

    // rolling state: [array][row-in-pair][age]; ct post-shift: [1]=c(p), [0]=c(p-1)
    float dx[2][2][3], dy[2][2][3], sm[2][2][3], ct[2][2][2];
    #pragma unroll
    for (int a = 0; a < 2; ++a)
        #pragma unroll
        for (int o = 0; o < 2; ++o) {
            dx[a][o][0]=dx[a][o][1]=dx[a][o][2]=0.f;
            dy[a][o][0]=dy[a][o][1]=dy[a][o][2]=0.f;
            sm[a][o][0]=sm[a][o][1]=sm[a][o][2]=0.f;
            ct[a][o][0]=ct[a][o][1]=0.f;
        }
    float acc = 0.f;

    dma_pair(0);        // prefetch pairs 0 and 1 (6 DMA ops in flight)
    dma_pair(1);

    for (int s = 0; s < NPAIR; ++s) {
        // Wait for pair s's DMAs (and everything older). vmcnt(3) leaves the next
        // pair's 3 DMAs in flight in steady state -- never a full drain in-loop.
        // Pair-s's DMAs have >=11 younger VMEM ops (masks s-2, DMAs s-1, masks s-1),
        // so vmcnt(3) strictly covers them regardless of mask-load scheduling
        // (over-waiting on young mask loads is harmless).
        if (s < NPAIR - 1) {
            asm volatile("s_waitcnt vmcnt(3)" ::: "memory");
        } else {
            asm volatile("s_waitcnt vmcnt(0)" ::: "memory");
        }
        __builtin_amdgcn_sched_barrier(0);
        __builtin_amdgcn_s_barrier();       // raw barrier: no compiler-forced drain
        __builtin_amdgcn_sched_barrier(0);

        // Issue pair s+2 into the buffer whose readers (compute s-1) all finished
        // before the barrier above.
        if (s + 2 < NPAIR) dma_pair(s + 2);

        Mc = Mn; Mc1 = Mn1;
        if (s + 1 < NPAIR) load_mask(s + 1);   // masks for round s+1 outputs

        const float* buf = lds + (s % NBUF) * BUFFLOATS;

        #pragma unroll
        for (int q = 0; q < 2; ++q) {
            const int p = d0 - 1 + 2 * s + q;

            #pragma unroll
            for (int a = 0; a < 2; ++a) {
                const int ab = (a * 2 + q) * LPLANE + (2 * wv) * LROW + col + 3;
                float e[4][3];
                #pragma unroll
                for (int rr = 0; rr < 4; ++rr)
                    #pragma unroll
                    for (int d = 0; d < 3; ++d)
                        e[rr][d] = buf[ab + rr * LROW + d];   // conflict-free (round 4)

                float rs[4], rd[4];
                #pragma unroll
                for (int rr = 0; rr < 4; ++rr) {
                    rs[rr] = e[rr][0] + 2.f * e[rr][1] + e[rr][2];
                    rd[rr] = e[rr][2] - e[rr][0];
                }
                #pragma unroll
                for (int o = 0; o < 2; ++o) {   // o = row within pair
                    dx[a][o][0] = dx[a][o][1]; dx[a][o][1] = dx[a][o][2];
                    dx[a][o][2] = rd[o] + 2.f * rd[o+1] + rd[o+2];
                    sm[a][o][0] = sm[a][o][1]; sm[a][o][1] = sm[a][o][2];
                    sm[a][o][2] = rs[o] + 2.f * rs[o+1] + rs[o+2];
                    dy[a][o][0] = dy[a][o][1]; dy[a][o][1] = dy[a][o][2];
                    dy[a][o][2] = rs[o] - rs[o+2];
                    ct[a][o][0] = ct[a][o][1]; ct[a][o][1] = e[o+1][1];
                }
            }

            if (p >= d0 + 1) {              // output plane od = p-1; ct[..][0] = c(p-1)
                const float2 M = q ? Mc1 : Mc;
                #pragma unroll
                for (int o = 0; o < 2; ++o) {
                    float gxa = dx[0][o][0] + 2.f * dx[0][o][1] + dx[0][o][2];
                    float gya = dy[0][o][0] + 2.f * dy[0][o][1] + dy[0][o][2];
                    float gza = sm[0][o][0] - sm[0][o][2];
                    float gxb = dx[1][o][0] + 2.f * dx[1][o][1] + dx[1][o][2];
                    float gyb = dy[1][o][0] + 2.f * dy[1][o][1] + dy[1][o][2];
                    float gzb = sm[1][o][0] - sm[1][o][2];
                    float ga = __builtin_amdgcn_sqrtf(gxa * gxa + gya * gya + gza * gza + 1e-10f);
                    float gb = __builtin_amdgcn_sqrtf(gxb * gxb + gyb * gyb + gzb * gzb + 1e-10f);
                    float m  = o ? M.y : M.x;
                    float dm = ct[0][o][0] - ct[1][o][0];
                    float mse = dm * dm * m;
                    float dg  = gb - ga;
                    float mge = dg * dg * m;
                    // tanh(x) = 1 - 2/(e^{2x}+1), x >= 0; saturates via inf -> rcp -> 0
                    float ex = __expf(2.f * mge);
                    float t  = 1.f - 2.f * __builtin_amdgcn_rcpf(ex + 1.f);
                    acc += mse * (1.f + t);
                }
            }
        }
    }

    // block reduction
    float v = acc;
    #pragma unroll
    for (int o = 32; o > 0; o >>= 1) v += __shfl_down(v, o, 64);
    if ((tid & 63) == 0) red[tid >> 6] = v;
    __syncthreads();
    if (tid == 0) {
        partials[(size_t)blockIdx.z * (gridDim.x * gridDim.y)
                 + (size_t)blockIdx.y * gridDim.x + blockIdx.x]
            = red[0] + red[1] + red[2] + red[3];
    }
}

__global__ __launch_bounds__(256) void reduce_final(
    const float* __restrict__ partials, int n, float* __restrict__ out)
{
    int tid = threadIdx.x;
    double s = 0.0;
    for (int i = tid; i < n; i += 256) s += (double)partials[i];
    #pragma unroll
    for (int o = 32; o > 0; o >>= 1) s += __shfl_down(s, o, 64);
    __shared__ double red[4];
    if ((tid & 63) == 0) red[tid >> 6] = s;
    __syncthreads();
    if (tid == 0) {
        double t = red[0] + red[1] + red[2] + red[3];
        const double ntot = (double)BATCH * (double)DEPTH * (double)H * (double)W;
        out[0] = (float)(t / ntot);
    }
}

extern "C" void kernel_launch(void* const* d_in, const int* in_sizes, int n_in,
                              void* d_out, int out_size, void* d_ws, size_t ws_size,
                              hipStream_t stream) {
    const float* pred = (const float*)d_in[0];
    const float* gt   = (const float*)d_in[1];
    const float* mask = (const float*)d_in[2];
    float* partials = (float*)d_ws;

    dim3 grid((W / TW) * (H / TH), DEPTH / DC, BATCH);   // 72 x 16 x 2 = 2304
    sobel_loss_part<<<grid, 256, 0, stream>>>(pred, gt, mask, partials);

    int nparts = grid.x * grid.y * grid.z;
    reduce_final<<<1, 256, 0, stream>>>(partials, nparts, (float*)d_out);
}